// Round 11
// baseline (305.713 us; speedup 1.0000x reference)
//
#include <hip/hip_runtime.h>
#include <hip/hip_bf16.h>

// SAGEMeanConv: out = relu((segment_sum(h_self[src], dst) + h_self) / (deg+1))
// Round 11: revert to multi-launch (cooperative launch failed 2x), but cut
// 5 launches -> 3:
//  K1: per-chunk LDS hist -> global hist atomics + Wt convert; LAST block
//      (device atomic ticket) scans 782 totals -> bucket_base/total/gcursor.
//  K2: gemm (391 blocks, barrier-free, B fully LDS-resident) U scatter (128):
//      per-chunk LDS hist, one atomicAdd(&gcursor[b],h) per (chunk,bucket) to
//      reserve a contiguous run, write runs (single-writer ~64B runs as R5).
//  K3: per-bucket LDS counting sort + fused gather/finalize (R8 unchanged).

#define IN_FEATS 256
#define OUT_FEATS 128
#define NUM_NODES 100000
#define NUM_EDGES 1600000

#define NB 782            // buckets of 128 nodes
#define EC 128            // edge chunks
#define CHUNK_E 12500     // edges per chunk
#define BCAP 3072         // max edges/bucket
#define GEMM_BLOCKS 391   // 256 rows per block

typedef __attribute__((ext_vector_type(8))) short short8;
typedef __attribute__((ext_vector_type(8))) unsigned short ushort8;
typedef __attribute__((ext_vector_type(4))) float f32x4;

static __device__ inline unsigned short f2bfu(float x) {
    union { __hip_bfloat16 h; unsigned short u; } c;
    c.h = __float2bfloat16(x);
    return c.u;
}
static __device__ inline ushort2 f2bfu2(float x, float y) {
    union { __hip_bfloat162 h; ushort2 u; } c;
    c.h = __float22bfloat162_rn(make_float2(x, y));
    return c.u;
}
static __device__ inline float bf2f(unsigned short h) {
    return __uint_as_float((unsigned)h << 16);
}

// ---------------- K1: hist (b<128) + Wt convert (b>=128); last block scans ----------------
__global__ __launch_bounds__(256) void hist_convert_scan(
    const float* __restrict__ W, unsigned short* __restrict__ Wt,
    const int* __restrict__ dst, int* __restrict__ hist, int* __restrict__ done,
    int* __restrict__ bucket_base, int* __restrict__ bucket_total,
    int* __restrict__ gcursor)
{
    __shared__ int lh[NB];
    __shared__ int sd[256];
    __shared__ int last_flag;
    int b = blockIdx.x, t = threadIdx.x;

    if (b < 128) {
        for (int i = t; i < NB; i += 256) lh[i] = 0;
        __syncthreads();
        const int4* dp = (const int4*)(dst + b * CHUNK_E);
        for (int i = t; i < CHUNK_E / 4; i += 256) {
            int4 d4 = dp[i];
            atomicAdd(&lh[d4.x >> 7], 1);
            atomicAdd(&lh[d4.y >> 7], 1);
            atomicAdd(&lh[d4.z >> 7], 1);
            atomicAdd(&lh[d4.w >> 7], 1);
        }
        __syncthreads();
        for (int i = t; i < NB; i += 256) {
            int h = lh[i];
            if (h) atomicAdd(&hist[i], h);
        }
    } else {
        int i = (b - 128) * 256 + t;     // 128 blocks * 256 = 32768 exact
        int n = i >> 8;
        int k = i & 255;
        Wt[i] = f2bfu(W[(size_t)k * OUT_FEATS + n]);
    }

    // ---- last-block ticket: the final block scans the 782 bucket totals ----
    __threadfence();
    __syncthreads();
    if (t == 0) last_flag = (atomicAdd(done, 1) == 255);   // grid = 256 blocks
    __syncthreads();
    if (last_flag) {
        int base = t * 4;
        int v0 = 0, v1 = 0, v2 = 0, v3 = 0;
        if (base + 0 < NB) v0 = atomicAdd(&hist[base + 0], 0);
        if (base + 1 < NB) v1 = atomicAdd(&hist[base + 1], 0);
        if (base + 2 < NB) v2 = atomicAdd(&hist[base + 2], 0);
        if (base + 3 < NB) v3 = atomicAdd(&hist[base + 3], 0);
        int s = v0 + v1 + v2 + v3;
        sd[t] = s;
        __syncthreads();
        for (int o = 1; o < 256; o <<= 1) {
            int x = (t >= o) ? sd[t - o] : 0;
            __syncthreads();
            sd[t] += x;
            __syncthreads();
        }
        int e0 = sd[t] - s, e1 = e0 + v0, e2 = e1 + v1, e3 = e2 + v2;
        if (base + 0 < NB) { bucket_base[base + 0] = e0; bucket_total[base + 0] = v0; gcursor[base + 0] = e0; }
        if (base + 1 < NB) { bucket_base[base + 1] = e1; bucket_total[base + 1] = v1; gcursor[base + 1] = e1; }
        if (base + 2 < NB) { bucket_base[base + 2] = e2; bucket_total[base + 2] = v2; gcursor[base + 2] = e2; }
        if (base + 3 < NB) { bucket_base[base + 3] = e3; bucket_total[base + 3] = v3; gcursor[base + 3] = e3; }
    }
}

// ---------------- K2: gemm (b<391) U chunk-scatter (391<=b<519), 512 thr ----------------
__global__ __launch_bounds__(512, 4) void gemm_scatter(
    const float* __restrict__ feat, const unsigned short* __restrict__ Wt,
    unsigned short* __restrict__ hself16, int M,
    const int* __restrict__ src, const int* __restrict__ dst,
    int* __restrict__ gcursor, int* __restrict__ bedges)
{
    __shared__ char smem_raw[65536];
    const int tid = threadIdx.x;

    if (blockIdx.x >= GEMM_BLOCKS) {
        // ---------------- scatter path (dynamic run reservation) ----------------
        int c = blockIdx.x - GEMM_BLOCKS;          // chunk 0..127
        int* lh = (int*)smem_raw;                  // hist, then run cursors
        for (int i = tid; i < NB; i += 512) lh[i] = 0;
        __syncthreads();
        const int4* dp = (const int4*)(dst + c * CHUNK_E);
        for (int i = tid; i < CHUNK_E / 4; i += 512) {
            int4 d4 = dp[i];
            atomicAdd(&lh[d4.x >> 7], 1);
            atomicAdd(&lh[d4.y >> 7], 1);
            atomicAdd(&lh[d4.z >> 7], 1);
            atomicAdd(&lh[d4.w >> 7], 1);
        }
        __syncthreads();
        for (int i = tid; i < NB; i += 512) {
            int h = lh[i];
            lh[i] = h ? atomicAdd(&gcursor[i], h) : 0;   // reserve contiguous run
        }
        __syncthreads();
        const int4* sp = (const int4*)(src + c * CHUNK_E);
        for (int i = tid; i < CHUNK_E / 4; i += 512) {
            int4 d4 = dp[i];
            int4 s4 = sp[i];
            int dv[4] = { d4.x, d4.y, d4.z, d4.w };
            int sv[4] = { s4.x, s4.y, s4.z, s4.w };
#pragma unroll
            for (int q = 0; q < 4; ++q) {
                int d = dv[q];
                int slot = atomicAdd(&lh[d >> 7], 1);
                bedges[slot] = sv[q] | ((d & 127) << 17);
            }
        }
        return;
    }

    // ---------------- gemm path (R8 unchanged) ----------------
    unsigned short* Bl = (unsigned short*)smem_raw;   // B: [n=128][k-granule swizzled]
    {
        int n = tid >> 2;                    // 0..127
        int gbase = (tid & 3) * 8;           // 0,8,16,24
#pragma unroll
        for (int j = 0; j < 8; ++j) {
            int g = gbase + j;
            ushort8 v = *(const ushort8*)(Wt + (size_t)n * IN_FEATS + g * 8);
            *(ushort8*)(Bl + n * IN_FEATS + ((g ^ (n & 7)) * 8)) = v;
        }
    }
    __syncthreads();

    const int w  = tid >> 6;                 // wave 0..7, owns rows w*32..+31
    const int l  = tid & 63;
    const int lf = l & 15;
    const int lg = (l >> 4) & 3;
    const int bm0 = blockIdx.x * 256;
    const int rbase = bm0 + w * 32;

    f32x4 acc[2][8];
#pragma unroll
    for (int mt = 0; mt < 2; ++mt)
#pragma unroll
        for (int nt = 0; nt < 8; ++nt)
            acc[mt][nt] = (f32x4){0.f, 0.f, 0.f, 0.f};

#pragma unroll 2
    for (int k0 = 0; k0 < IN_FEATS; k0 += 32) {
        int k8 = k0 >> 3;
        short8 af[2];
#pragma unroll
        for (int mt = 0; mt < 2; ++mt) {
            int grow = rbase + mt * 16 + lf;
            if (grow < M) {
                const float4* ap = (const float4*)(feat + (size_t)grow * IN_FEATS + k0 + lg * 8);
                float4 f0 = ap[0];
                float4 f1 = ap[1];
                ushort2 c0 = f2bfu2(f0.x, f0.y);
                ushort2 c1 = f2bfu2(f0.z, f0.w);
                ushort2 c2 = f2bfu2(f1.x, f1.y);
                ushort2 c3 = f2bfu2(f1.z, f1.w);
                af[mt] = (short8){ (short)c0.x, (short)c0.y, (short)c1.x, (short)c1.y,
                                   (short)c2.x, (short)c2.y, (short)c3.x, (short)c3.y };
            } else {
                af[mt] = (short8){ 0, 0, 0, 0, 0, 0, 0, 0 };
            }
        }
#pragma unroll
        for (int nh = 0; nh < 2; ++nh) {
            short8 bf[4];
#pragma unroll
            for (int q = 0; q < 4; ++q) {
                int nt = nh * 4 + q;
                int n = nt * 16 + lf;
                int g = (k8 + lg) ^ (lf & 7);
                bf[q] = *(const short8*)(Bl + n * IN_FEATS + g * 8);
            }
#pragma unroll
            for (int q = 0; q < 4; ++q) {
                int nt = nh * 4 + q;
                acc[0][nt] = __builtin_amdgcn_mfma_f32_16x16x32_bf16(af[0], bf[q], acc[0][nt], 0, 0, 0);
                acc[1][nt] = __builtin_amdgcn_mfma_f32_16x16x32_bf16(af[1], bf[q], acc[1][nt], 0, 0, 0);
            }
        }
    }

    // ---- epilogue: reuse LDS (B dead) for row-major transpose, coalesced stores ----
    __syncthreads();
    unsigned short* ep = (unsigned short*)smem_raw;   // [256 rows][128 cols]
#pragma unroll
    for (int mt = 0; mt < 2; ++mt)
#pragma unroll
        for (int nt = 0; nt < 8; ++nt)
#pragma unroll
            for (int r = 0; r < 4; ++r) {
                int row = w * 32 + mt * 16 + lg * 4 + r;
                ep[row * 128 + nt * 16 + lf] = f2bfu(acc[mt][nt][r]);
            }
    __syncthreads();
#pragma unroll
    for (int i = 0; i < 8; ++i) {
        int lrow = w * 32 + i * 4 + (l >> 4);
        ushort8 v = *(const ushort8*)(ep + lrow * 128 + (l & 15) * 8);
        int grow = bm0 + lrow;
        if (grow < M)
            *(ushort8*)(hself16 + (size_t)grow * OUT_FEATS + (l & 15) * 8) = v;
    }
}

// ---------------- K3: per-bucket LDS counting sort + fused gather/finalize ----------------
__global__ __launch_bounds__(512, 8) void sort_gather(
    const int* __restrict__ bucket_base, const int* __restrict__ bucket_total,
    const int* __restrict__ bedges, const unsigned short* __restrict__ hself16,
    float* __restrict__ out)
{
    __shared__ int sorted[BCAP];
    __shared__ int cnt[128], off[128], cursor[128], sd[128];

    int b = blockIdx.x, t = threadIdx.x;
    int base = bucket_base[b];
    int tot = bucket_total[b];
    if (tot > BCAP) tot = BCAP;
    int nnodes = NUM_NODES - b * 128;
    if (nnodes > 128) nnodes = 128;

    if (t < 128) cnt[t] = 0;
    __syncthreads();
    for (int i = t; i < tot; i += 512)
        atomicAdd(&cnt[bedges[base + i] >> 17], 1);
    __syncthreads();
    if (t < 128) sd[t] = cnt[t];
    __syncthreads();
    for (int o = 1; o < 128; o <<= 1) {
        int x = 0;
        if (t < 128 && t >= o) x = sd[t - o];
        __syncthreads();
        if (t < 128) sd[t] += x;
        __syncthreads();
    }
    if (t < 128) { int e = sd[t] - cnt[t]; off[t] = e; cursor[t] = e; }
    __syncthreads();
    for (int i = t; i < tot; i += 512) {
        int e = bedges[base + i];           // re-read (L2-hot)
        int r = atomicAdd(&cursor[e >> 17], 1);
        sorted[r] = e & 0x1FFFF;
    }
    __syncthreads();

    int w = t >> 6, l = t & 63, lg = l >> 4, lf = l & 15;
    for (int ln = w; ln < nnodes; ln += 8) {
        int beg = off[ln];
        int end = beg + cnt[ln];
        float acc[8];
#pragma unroll
        for (int i = 0; i < 8; ++i) acc[i] = 0.f;
        for (int j0 = beg; j0 < end; j0 += 16) {
            int  jj[4];
            bool pp[4];
            int  ss[4];
#pragma unroll
            for (int q = 0; q < 4; ++q) {
                jj[q] = j0 + q * 4 + lg;
                pp[q] = jj[q] < end;
                ss[q] = pp[q] ? sorted[jj[q]] : 0;
            }
            ushort8 h[4];
#pragma unroll
            for (int q = 0; q < 4; ++q)
                h[q] = *(const ushort8*)(hself16 + (size_t)ss[q] * OUT_FEATS + lf * 8);
#pragma unroll
            for (int q = 0; q < 4; ++q)
                if (pp[q]) {
#pragma unroll
                    for (int i = 0; i < 8; ++i) acc[i] += bf2f(h[q][i]);
                }
        }
#pragma unroll
        for (int i = 0; i < 8; ++i) {
            acc[i] += __shfl_xor(acc[i], 16, 64);
            acc[i] += __shfl_xor(acc[i], 32, 64);
        }
        if (lg == 0) {
            int n = b * 128 + ln;
            float inv = 1.0f / (float)(end - beg + 1);
            ushort8 hs = *(const ushort8*)(hself16 + (size_t)n * OUT_FEATS + lf * 8);
            float v[8];
#pragma unroll
            for (int i = 0; i < 8; ++i)
                v[i] = fmaxf((acc[i] + bf2f(hs[i])) * inv, 0.f);
            float4* op = (float4*)(out + (size_t)n * OUT_FEATS + lf * 8);
            op[0] = make_float4(v[0], v[1], v[2], v[3]);
            op[1] = make_float4(v[4], v[5], v[6], v[7]);
        }
    }
}

extern "C" void kernel_launch(void* const* d_in, const int* in_sizes, int n_in,
                              void* d_out, int out_size, void* d_ws, size_t ws_size,
                              hipStream_t stream) {
    const float* feat = (const float*)d_in[0];
    const float* W    = (const float*)d_in[1];
    const int*   src  = (const int*)d_in[2];
    const int*   dst  = (const int*)d_in[3];
    float* out = (float*)d_out;

    char* ws = (char*)d_ws;
    unsigned short* hself16 = (unsigned short*)ws;                 // 25,600,000 B
    unsigned short* Wt      = (unsigned short*)(ws + 25600000);    //     65,536 B
    int* hist         = (int*)(ws + 25665536);                     //      3,128 B
    int* done         = (int*)(ws + 25668664);                     //          4 B
    int* bucket_base  = (int*)(ws + 25668672);                     //      3,128 B
    int* bucket_total = (int*)(ws + 25671808);                     //      3,128 B
    int* gcursor      = (int*)(ws + 25674944);                     //      3,128 B
    int* bedges       = (int*)(ws + 25678080);                     //  6,400,000 B

    // zero hist + done (adjacent, 3132 B)
    hipMemsetAsync(hist, 0, 3132, stream);

    // K1: hist + Wt convert; last block scans -> bucket_base/total, gcursor
    hist_convert_scan<<<256, 256, 0, stream>>>(
        W, Wt, dst, hist, done, bucket_base, bucket_total, gcursor);

    // K2: gemm U dynamic-reservation scatter
    gemm_scatter<<<GEMM_BLOCKS + EC, 512, 0, stream>>>(
        feat, Wt, hself16, NUM_NODES, src, dst, gcursor, bedges);

    // K3: per-bucket sort + gather + finalize
    sort_gather<<<NB, 512, 0, stream>>>(bucket_base, bucket_total, bedges, hself16, out);
}